// Round 4
// baseline (203.812 us; speedup 1.0000x reference)
//
#include <hip/hip_runtime.h>

#define S_LEN 2048
#define DMODEL 1024
#define HEADS 8
#define DH 128
#define NQKV 6144
#define SCALE 0.08838834764831845f

typedef unsigned short u16;
typedef short s16x8 __attribute__((ext_vector_type(8)));
typedef short s16x4 __attribute__((ext_vector_type(4)));
typedef float f32x4 __attribute__((ext_vector_type(4)));

static __device__ __forceinline__ f32x4 mfma16(s16x8 a, s16x8 b, f32x4 c) {
  return __builtin_amdgcn_mfma_f32_16x16x32_bf16(a, b, c, 0, 0, 0);
}
static __device__ __forceinline__ u16 f2b(float f) {
  union { float f; unsigned u; } v; v.f = f;
  unsigned r = v.u + 0x7fffu + ((v.u >> 16) & 1u);
  return (u16)(r >> 16);
}
static __device__ __forceinline__ float b2f(u16 s) {
  union { unsigned u; float f; } v; v.u = ((unsigned)s) << 16;
  return v.f;
}
// async global->LDS, 16B per lane; lds dest = uniform base + lane*16
static __device__ __forceinline__ void gll16(const u16* g, u16* l) {
  __builtin_amdgcn_global_load_lds(
      (const __attribute__((address_space(1))) unsigned int*)g,
      (__attribute__((address_space(3))) unsigned int*)l, 16, 0, 0);
}

// chunk = 2 key tiles
static __device__ const int PFX2[16] = {0,1,2,4,6,9,12,16,20,25,30,36,42,49,56,64};
static __device__ const int SQB2[72] = {
  0,1,2,2,3,3,4,4,4,5,5,5,6,6,6,6,7,7,7,7,
  8,8,8,8,8,9,9,9,9,9,10,10,10,10,10,10,11,11,11,11,11,11,
  12,12,12,12,12,12,12,13,13,13,13,13,13,13,
  14,14,14,14,14,14,14,14,15,15,15,15,15,15,15,15};

// ---------------------------------------------------------------- cast x -> bf16
__global__ void k_cast(const float* __restrict__ in, u16* __restrict__ out) {
  int i = blockIdx.x * 256 + threadIdx.x;
  float4 v = reinterpret_cast<const float4*>(in)[i];
  s16x4 o;
  o[0] = (short)f2b(v.x); o[1] = (short)f2b(v.y);
  o[2] = (short)f2b(v.z); o[3] = (short)f2b(v.w);
  reinterpret_cast<s16x4*>(out)[i] = o;
}

// ------------------------------------------- transpose+cast: out[c][r] = in[r][c]
__global__ void k_transpose(const float* __restrict__ in, u16* __restrict__ out,
                            int R, int C) {
  __shared__ float tile[32][33];
  int c0 = blockIdx.x * 32, r0 = blockIdx.y * 32;
#pragma unroll
  for (int k = 0; k < 4; k++)
    tile[threadIdx.y + k * 8][threadIdx.x] =
        in[(size_t)(r0 + threadIdx.y + k * 8) * C + c0 + threadIdx.x];
  __syncthreads();
#pragma unroll
  for (int k = 0; k < 4; k++)
    out[(size_t)(c0 + threadIdx.y + k * 8) * R + r0 + threadIdx.x] =
        f2b(tile[threadIdx.x][threadIdx.y + k * 8]);
}

// ---------------------------------------------------------------- GEMM (m97-style)
// C[M,N] = A[M,K] @ Bt[N,K]^T, K=1024, 128x128 tile, BK=64, global_load_lds w16,
// XOR-swizzled LDS (linear [128][64], byte ^= ((row&7)<<4)).
// MODE 0: 1-D grid 768, n-chunk XCD swizzle; t in {2,5} stored transposed; scale 0,3.
// MODE 1: 2-D grid, f32 out [M][1024].
template <int MODE>
__global__ void __launch_bounds__(256, 3)
k_gemm2(const u16* __restrict__ A, const u16* __restrict__ Bt,
        u16* __restrict__ outb, float* __restrict__ outf) {
  __shared__ u16 As[128 * 64];
  __shared__ u16 Bs[128 * 64];
  const int tid = threadIdx.x;
  int m0, n0;
  if (MODE == 0) {
    int m = blockIdx.x / 48, j = blockIdx.x % 48;
    int n = (j & 7) * 6 + (j >> 3);  // XCD (bid%8) owns n in [6*xcd, 6*xcd+6)
    m0 = m * 128; n0 = n * 128;
  } else {
    m0 = blockIdx.y * 128; n0 = blockIdx.x * 128;
  }
  const int w = tid >> 6, l = tid & 63;
  const int wm = (w >> 1) * 64, wn = (w & 1) * 64;
  const int lr = l & 15, lg = l >> 4;
  f32x4 acc[4][4] = {};
  for (int k0 = 0; k0 < DMODEL; k0 += 64) {
    __syncthreads();
#pragma unroll
    for (int j = 0; j < 8; j++) {
      int c = w * 8 + j;          // 0..31; <16 -> A chunk, else B chunk
      int cc = c & 15;            // chunk within tile: rows cc*8..cc*8+7
      int r = cc * 8 + (l >> 3);
      int s = l & 7;              // 16B slot within 128B row
      const u16* src = (c < 16 ? A + (size_t)(m0 + r) * DMODEL
                               : Bt + (size_t)(n0 + r) * DMODEL)
                       + k0 + ((s ^ (r & 7)) * 8);
      gll16(src, (c < 16 ? As : Bs) + cc * 8 * 64);
    }
    asm volatile("s_waitcnt vmcnt(0)" ::: "memory");
    __syncthreads();
    s16x8 a[2][4], b[2][4];
#pragma unroll
    for (int hh = 0; hh < 2; hh++)
#pragma unroll
      for (int i = 0; i < 4; i++) {
        int ra = wm + i * 16 + lr;
        int oa = (ra * 128 + hh * 64 + lg * 16) ^ ((lr & 7) << 4);
        a[hh][i] = *reinterpret_cast<const s16x8*>((const char*)As + oa);
        int rb = wn + i * 16 + lr;
        int ob = (rb * 128 + hh * 64 + lg * 16) ^ ((lr & 7) << 4);
        b[hh][i] = *reinterpret_cast<const s16x8*>((const char*)Bs + ob);
      }
#pragma unroll
    for (int hh = 0; hh < 2; hh++)
#pragma unroll
      for (int i = 0; i < 4; i++)
#pragma unroll
        for (int j = 0; j < 4; j++)
          acc[i][j] = mfma16(a[hh][i], b[hh][j], acc[i][j]);
  }
  if (MODE == 0) {
    const int n = n0 >> 7;
    const int t = n >> 3, h = n & 7;
    u16* dst = outb + (size_t)(t * HEADS + h) * S_LEN * DH;
    if (t == 2 || t == 5) {
      // transposed: [d=128][s=2048]; pack 4 consecutive rows -> 8B store
#pragma unroll
      for (int i = 0; i < 4; i++)
#pragma unroll
        for (int j = 0; j < 4; j++) {
          int col = wn + j * 16 + lr;
          int row0 = m0 + wm + i * 16 + lg * 4;
          s16x4 p;
#pragma unroll
          for (int e = 0; e < 4; e++) p[e] = (short)f2b(acc[i][j][e]);
          *reinterpret_cast<s16x4*>(dst + (size_t)col * S_LEN + row0) = p;
        }
    } else {
      const float sc = (t == 0 || t == 3) ? SCALE : 1.0f;
#pragma unroll
      for (int i = 0; i < 4; i++)
#pragma unroll
        for (int j = 0; j < 4; j++)
#pragma unroll
          for (int e = 0; e < 4; e++) {
            int row = m0 + wm + i * 16 + lg * 4 + e;
            int col = wn + j * 16 + lr;
            dst[(size_t)row * DH + col] = f2b(acc[i][j][e] * sc);
          }
    }
  } else {
#pragma unroll
    for (int i = 0; i < 4; i++)
#pragma unroll
      for (int j = 0; j < 4; j++)
#pragma unroll
        for (int e = 0; e < 4; e++) {
          int row = m0 + wm + i * 16 + lg * 4 + e;
          int col = n0 + wn + j * 16 + lr;
          outf[(size_t)row * DMODEL + col] = acc[i][j][e];
        }
  }
}

// ---------------------------------------------------------------- diag correction
// per (qb, h): corr[row][col] = silu( (sigmoid(quku) masked col>row) @ vu )
// 1-D grid 128: h = bid&7 (XCD affinity), qb = bid>>3
__global__ void __launch_bounds__(256)
k_diag(const u16* __restrict__ qkvb, u16* __restrict__ corr) {
  __shared__ u16 PB[128][136];
  const int h = blockIdx.x & 7, qb = blockIdx.x >> 3;
  const int tid = threadIdx.x;
  const int w = tid >> 6, l = tid & 63;
  const int lr = l & 15, lg = l >> 4;
  const size_t hs = (size_t)S_LEN * DH;
  const u16* qu = qkvb + (size_t)(0 * HEADS + h) * hs;
  const u16* ku = qkvb + (size_t)(1 * HEADS + h) * hs;
  const u16* vuT = qkvb + (size_t)(2 * HEADS + h) * hs;  // [128][2048]
  const int rq = qb * 128 + w * 32;
  const u16* kub = ku + (size_t)qb * 128 * DH;
  f32x4 acc2[2][8] = {};
#pragma unroll
  for (int ks = 0; ks < 4; ks++) {
    s16x8 a0 = *reinterpret_cast<const s16x8*>(qu + (size_t)(rq + lr) * DH + ks * 32 + lg * 8);
    s16x8 a1 = *reinterpret_cast<const s16x8*>(qu + (size_t)(rq + 16 + lr) * DH + ks * 32 + lg * 8);
#pragma unroll
    for (int nf = 0; nf < 8; nf++) {
      s16x8 b = *reinterpret_cast<const s16x8*>(kub + (size_t)(nf * 16 + lr) * DH + ks * 32 + lg * 8);
      acc2[0][nf] = mfma16(a0, b, acc2[0][nf]);
      acc2[1][nf] = mfma16(a1, b, acc2[1][nf]);
    }
  }
#pragma unroll
  for (int mf = 0; mf < 2; mf++)
#pragma unroll
    for (int nf = 0; nf < 8; nf++)
#pragma unroll
      for (int e = 0; e < 4; e++) {
        int row = w * 32 + mf * 16 + lg * 4 + e;
        int col = nf * 16 + lr;
        float x = acc2[mf][nf][e];
        PB[row][col] = f2b((col > row) ? 1.f / (1.f + __expf(-x)) : 0.f);
        acc2[mf][nf][e] = 0.f;
      }
  // su = la @ vu  (PB rows are wave-private; vuT rows from global)
#pragma unroll
  for (int ks = 0; ks < 4; ks++) {
    s16x8 p0 = *reinterpret_cast<const s16x8*>(&PB[w * 32 + lr][ks * 32 + lg * 8]);
    s16x8 p1 = *reinterpret_cast<const s16x8*>(&PB[w * 32 + 16 + lr][ks * 32 + lg * 8]);
#pragma unroll
    for (int nf = 0; nf < 8; nf++) {
      s16x8 b = *reinterpret_cast<const s16x8*>(
          vuT + (size_t)(nf * 16 + lr) * S_LEN + qb * 128 + ks * 32 + lg * 8);
      acc2[0][nf] = mfma16(p0, b, acc2[0][nf]);
      acc2[1][nf] = mfma16(p1, b, acc2[1][nf]);
    }
  }
  u16* cp = corr + (size_t)(h * 16 + qb) * 16384;
#pragma unroll
  for (int mf = 0; mf < 2; mf++)
#pragma unroll
    for (int nf = 0; nf < 8; nf++)
#pragma unroll
      for (int e = 0; e < 4; e++) {
        int row = w * 32 + mf * 16 + lg * 4 + e;
        int col = nf * 16 + lr;
        float x = acc2[mf][nf][e];
        cp[row * 128 + col] = f2b(x / (1.f + __expf(-x)));
      }
}

// ---------------------------------------------------------------- attention phase 1
// 1-D grid 576: h = bid&7 (all 72 slots of a head pin to one XCD -> K/V/Q L2-hit),
// slot = bid>>3. 512 thr / 8 waves x 16 q-rows; <=2 key tiles; V^T via
// global_load_lds + XOR swizzle; K direct from L2; PB wave-private.
__global__ void __launch_bounds__(512, 4)
k_attn1(const u16* __restrict__ qkvb, const u16* __restrict__ corr,
        u16* __restrict__ opA, u16* __restrict__ opB, float* __restrict__ ml) {
  __shared__ u16 VT[128 * 128];   // linear [d=128][j=128], swizzled content
  __shared__ u16 PB[128][72];     // P halves, wave-private rows
  const int h = blockIdx.x & 7, slot = blockIdx.x >> 3;
  const int qb = SQB2[slot];
  const int t0 = (slot - PFX2[qb]) * 2;
  const int t1 = min(t0 + 2, qb + 1);
  const int tid = threadIdx.x;
  const int w = tid >> 6, l = tid & 63;
  const int lr = l & 15, lg = l >> 4;
  const size_t hs = (size_t)S_LEN * DH;
  const u16* qc = qkvb + (size_t)(3 * HEADS + h) * hs;
  const u16* kc = qkvb + (size_t)(4 * HEADS + h) * hs;
  const u16* vcT = qkvb + (size_t)(5 * HEADS + h) * hs;  // [128][2048]
  const int rq = qb * 128 + w * 16;

  f32x4 accO[8] = {};
  float mrun[4], lrun[4];
#pragma unroll
  for (int e = 0; e < 4; e++) { mrun[e] = -INFINITY; lrun[e] = 0.f; }

  // initial V stage for t0 (wave w covers d-rows w*16..w*16+15)
#pragma unroll
  for (int i = 0; i < 4; i++) {
    int r = w * 16 + i * 4 + (l >> 4);
    int s = l & 15;
    const u16* src = vcT + (size_t)r * S_LEN + t0 * 128 + ((s ^ (r & 7)) * 8);
    gll16(src, VT + (w * 16 + i * 4) * 128);
  }
  // Q fragments hoisted out of the tile loop
  s16x8 aq[4];
#pragma unroll
  for (int ks = 0; ks < 4; ks++)
    aq[ks] = *reinterpret_cast<const s16x8*>(
        qc + (size_t)(rq + lr) * DH + ks * 32 + lg * 8);

  for (int t = t0; t < t1; t++) {
    const bool diag = (t == qb);
    const u16* kb = kc + (size_t)t * 128 * DH;
    f32x4 accS[8] = {};
#pragma unroll
    for (int ks = 0; ks < 4; ks++) {
#pragma unroll
      for (int nf = 0; nf < 8; nf++) {
        s16x8 b = *reinterpret_cast<const s16x8*>(kb + (size_t)(nf * 16 + lr) * DH + ks * 32 + lg * 8);
        accS[nf] = mfma16(aq[ks], b, accS[nf]);
      }
    }
    if (diag) {
      const u16* cp = corr + (size_t)(h * 16 + qb) * 16384;
#pragma unroll
      for (int nf = 0; nf < 8; nf++)
#pragma unroll
        for (int e = 0; e < 4; e++) {
          int row = w * 16 + lg * 4 + e;
          int col = nf * 16 + lr;
          if (col > row) accS[nf][e] = -INFINITY;
          else accS[nf][e] -= b2f(cp[row * 128 + col]);
        }
    }
    float fac[4];
#pragma unroll
    for (int e = 0; e < 4; e++) {
      float mx = accS[0][e];
#pragma unroll
      for (int nf = 1; nf < 8; nf++) mx = fmaxf(mx, accS[nf][e]);
#pragma unroll
      for (int off = 1; off < 16; off <<= 1) mx = fmaxf(mx, __shfl_xor(mx, off, 64));
      float mnew = fmaxf(mrun[e], mx);
      float f = __expf(mrun[e] - mnew);
      float rs = 0.f;
#pragma unroll
      for (int nf = 0; nf < 8; nf++) {
        float p = __expf(accS[nf][e] - mnew);
        accS[nf][e] = p;
        rs += p;
      }
#pragma unroll
      for (int off = 1; off < 16; off <<= 1) rs += __shfl_xor(rs, off, 64);
      lrun[e] = lrun[e] * f + rs;
      mrun[e] = mnew;
      fac[e] = f;
    }
#pragma unroll
    for (int nf = 0; nf < 8; nf++)
#pragma unroll
      for (int e = 0; e < 4; e++) accO[nf][e] *= fac[e];
    asm volatile("s_waitcnt vmcnt(0)" ::: "memory");
    __syncthreads();  // all waves' V stages landed
    // PV in two 64-key halves; PB rows are wave-private
#pragma unroll
    for (int h2 = 0; h2 < 2; h2++) {
#pragma unroll
      for (int jj = 0; jj < 4; jj++)
#pragma unroll
        for (int e = 0; e < 4; e++)
          PB[w * 16 + lg * 4 + e][jj * 16 + lr] = f2b(accS[h2 * 4 + jj][e]);
#pragma unroll
      for (int ks2 = 0; ks2 < 2; ks2++) {
        s16x8 p = *reinterpret_cast<const s16x8*>(&PB[w * 16 + lr][ks2 * 32 + lg * 8]);
#pragma unroll
        for (int nf = 0; nf < 8; nf++) {
          int o = ((nf * 16 + lr) * 256 + h2 * 128 + ks2 * 64 + lg * 16) ^ ((lr & 7) << 4);
          s16x8 bv = *reinterpret_cast<const s16x8*>((const char*)VT + o);
          accO[nf] = mfma16(p, bv, accO[nf]);
        }
      }
    }
    __syncthreads();  // all waves done reading VT
    if (t + 1 < t1) {
#pragma unroll
      for (int i = 0; i < 4; i++) {
        int r = w * 16 + i * 4 + (l >> 4);
        int s = l & 15;
        const u16* src = vcT + (size_t)r * S_LEN + (t + 1) * 128 + ((s ^ (r & 7)) * 8);
        gll16(src, VT + (w * 16 + i * 4) * 128);
      }
    }
  }
  const int gs = h * 72 + slot;
  u16* op = gs < 384 ? opA + (size_t)gs * 16384 : opB + (size_t)(gs - 384) * 16384;
#pragma unroll
  for (int nf = 0; nf < 8; nf++)
#pragma unroll
    for (int e = 0; e < 4; e++) {
      int row = w * 16 + lg * 4 + e;
      op[row * 128 + nf * 16 + lr] = f2b(accO[nf][e]);
    }
  if (lr == 0) {
    float* mlp = ml + (size_t)gs * 256;
#pragma unroll
    for (int e = 0; e < 4; e++) {
      int row = w * 16 + lg * 4 + e;
      mlp[row] = mrun[e];
      mlp[128 + row] = lrun[e];
    }
  }
}

// ---------------------------------------------------------------- phase 2 merge
// 1-D grid 128: h = bid&7 (same XCD as producer slots), qb = bid>>3
__global__ void __launch_bounds__(256)
k_attn2(const u16* __restrict__ opA, const u16* __restrict__ opB,
        const float* __restrict__ ml, u16* __restrict__ obuf) {
  const int h = blockIdx.x & 7, qb = blockIdx.x >> 3;
  const int nc = (qb >> 1) + 1;
  const int s0 = h * 72 + PFX2[qb];
  const int row = threadIdx.x >> 1, c0 = (threadIdx.x & 1) * 64;
  float mg = -INFINITY;
  for (int c = 0; c < nc; c++) mg = fmaxf(mg, ml[(size_t)(s0 + c) * 256 + row]);
  float acc[64];
#pragma unroll
  for (int k = 0; k < 64; k++) acc[k] = 0.f;
  float lsum = 0.f;
  for (int c = 0; c < nc; c++) {
    int gs = s0 + c;
    const float* mlp = ml + (size_t)gs * 256;
    float f = __expf(mlp[row] - mg);
    lsum += f * mlp[128 + row];
    const u16* p = (gs < 384 ? opA + (size_t)gs * 16384
                             : opB + (size_t)(gs - 384) * 16384) + row * 128 + c0;
#pragma unroll
    for (int k = 0; k < 8; k++) {
      s16x8 v = *reinterpret_cast<const s16x8*>(p + k * 8);
#pragma unroll
      for (int j = 0; j < 8; j++) acc[k * 8 + j] += f * b2f((u16)v[j]);
    }
  }
  float inv = 1.f / lsum;
  u16* dst = obuf + (size_t)(qb * 128 + row) * DMODEL + h * DH + c0;
#pragma unroll
  for (int k = 0; k < 8; k++) {
    s16x8 o;
#pragma unroll
    for (int j = 0; j < 8; j++) o[j] = (short)f2b(acc[k * 8 + j] * inv);
    *reinterpret_cast<s16x8*>(dst + k * 8) = o;
  }
}

// ---------------------------------------------------------------- launcher
extern "C" void kernel_launch(void* const* d_in, const int* in_sizes, int n_in,
                              void* d_out, int out_size, void* d_ws, size_t ws_size,
                              hipStream_t stream) {
  (void)in_sizes; (void)n_in; (void)out_size; (void)ws_size;
  const float* x = (const float*)d_in[0];
  const float* wqkv = (const float*)d_in[1];
  const float* wout = (const float*)d_in[2];
  char* ws = (char*)d_ws;
  u16* xb    = (u16*)(ws + 0);          // 4 MB; dead after gemm0
  u16* corrb = (u16*)(ws + 0);          // k_diag output (reuses xb)
  u16* wqT   = (u16*)(ws + 4194304);    // 12.58 MB; dead after gemm0
  u16* opB   = (u16*)(ws + 4194304);    // attn partials slots 384..575 (6.29 MB)
  float* mlb = (float*)(ws + 10485760); // 576*256*4 = 0.59 MB
  u16* woT   = (u16*)(ws + 16777216);   // 2 MB
  u16* qkvb  = (u16*)(ws + 18874368);   // 24 MB: [qu|ku|vuT|qc|kc|vcT] 4 MB each
  u16* opA   = (u16*)(ws + 18874368);   // attn partials slots 0..383 (12 MB,
                                        //   overwrites qu/ku/vuT after k_diag)
  u16* obuf  = (u16*)(ws + 44040192);   // 4 MB
  float* out = (float*)d_out;

  k_cast<<<2048, 256, 0, stream>>>(x, xb);
  k_transpose<<<dim3(192, 32), dim3(32, 8), 0, stream>>>(wqkv, wqT, DMODEL, NQKV);
  k_transpose<<<dim3(32, 32), dim3(32, 8), 0, stream>>>(wout, woT, DMODEL, DMODEL);
  k_gemm2<0><<<768, 256, 0, stream>>>(xb, wqT, qkvb, nullptr);
  k_diag<<<128, 256, 0, stream>>>(qkvb, corrb);
  k_attn1<<<576, 512, 0, stream>>>(qkvb, corrb, opA, opB, mlb);
  k_attn2<<<128, 256, 0, stream>>>(opA, opB, mlb, obuf);
  k_gemm2<1><<<dim3(8, 16), 256, 0, stream>>>(obuf, woT, nullptr, out);
}

// Round 5
// 198.207 us; speedup vs baseline: 1.0283x; 1.0283x over previous
//
#include <hip/hip_runtime.h>

#define S_LEN 2048
#define DMODEL 1024
#define HEADS 8
#define DH 128
#define NQKV 6144
#define SCALE 0.08838834764831845f

typedef unsigned short u16;
typedef short s16x8 __attribute__((ext_vector_type(8)));
typedef short s16x4 __attribute__((ext_vector_type(4)));
typedef float f32x4 __attribute__((ext_vector_type(4)));

static __device__ __forceinline__ f32x4 mfma16(s16x8 a, s16x8 b, f32x4 c) {
  return __builtin_amdgcn_mfma_f32_16x16x32_bf16(a, b, c, 0, 0, 0);
}
static __device__ __forceinline__ u16 f2b(float f) {
  union { float f; unsigned u; } v; v.f = f;
  unsigned r = v.u + 0x7fffu + ((v.u >> 16) & 1u);
  return (u16)(r >> 16);
}
static __device__ __forceinline__ float b2f(u16 s) {
  union { unsigned u; float f; } v; v.u = ((unsigned)s) << 16;
  return v.f;
}
// async global->LDS, 16B per lane; lds dest = uniform base + lane*16
static __device__ __forceinline__ void gll16(const u16* g, u16* l) {
  __builtin_amdgcn_global_load_lds(
      (const __attribute__((address_space(1))) unsigned int*)g,
      (__attribute__((address_space(3))) unsigned int*)l, 16, 0, 0);
}

// chunk = 2 key tiles
static __device__ const int PFX2[16] = {0,1,2,4,6,9,12,16,20,25,30,36,42,49,56,64};
static __device__ const int SQB2[72] = {
  0,1,2,2,3,3,4,4,4,5,5,5,6,6,6,6,7,7,7,7,
  8,8,8,8,8,9,9,9,9,9,10,10,10,10,10,10,11,11,11,11,11,11,
  12,12,12,12,12,12,12,13,13,13,13,13,13,13,
  14,14,14,14,14,14,14,14,15,15,15,15,15,15,15,15};

// ---------------------------------------------------------------- cast x -> bf16
__global__ void k_cast(const float* __restrict__ in, u16* __restrict__ out) {
  int i = blockIdx.x * 256 + threadIdx.x;
  float4 v = reinterpret_cast<const float4*>(in)[i];
  s16x4 o;
  o[0] = (short)f2b(v.x); o[1] = (short)f2b(v.y);
  o[2] = (short)f2b(v.z); o[3] = (short)f2b(v.w);
  reinterpret_cast<s16x4*>(out)[i] = o;
}

// ------------------------------------------- transpose+cast: out[c][r] = in[r][c]
__global__ void k_transpose(const float* __restrict__ in, u16* __restrict__ out,
                            int R, int C) {
  __shared__ float tile[32][33];
  int c0 = blockIdx.x * 32, r0 = blockIdx.y * 32;
#pragma unroll
  for (int k = 0; k < 4; k++)
    tile[threadIdx.y + k * 8][threadIdx.x] =
        in[(size_t)(r0 + threadIdx.y + k * 8) * C + c0 + threadIdx.x];
  __syncthreads();
#pragma unroll
  for (int k = 0; k < 4; k++)
    out[(size_t)(c0 + threadIdx.y + k * 8) * R + r0 + threadIdx.x] =
        f2b(tile[threadIdx.x][threadIdx.y + k * 8]);
}

// ---------------------------------------------------------------- GEMM (m97-style)
// C[M,N] = A[M,K] @ Bt[N,K]^T, K=1024, 128x128 tile, BK=64, global_load_lds w16,
// XOR-swizzled LDS (linear [128][64], byte ^= ((row&7)<<4)).
// MODE 0: 1-D grid 768; XCD x computes n-tiles with n&7==x (head x -> XCD x,
//         matching k_attn1's consumer pinning). t in {2,5} transposed; scale 0,3.
// MODE 1: 2-D grid, f32 out [M][1024].
template <int MODE>
__global__ void __launch_bounds__(256, 3)
k_gemm2(const u16* __restrict__ A, const u16* __restrict__ Bt,
        u16* __restrict__ outb, float* __restrict__ outf) {
  __shared__ u16 As[128 * 64];
  __shared__ u16 Bs[128 * 64];
  const int tid = threadIdx.x;
  int m0, n0;
  if (MODE == 0) {
    int m = blockIdx.x / 48, j = blockIdx.x % 48;
    int n = (j & 7) + 8 * (j >> 3);  // XCD (j&7) owns all n with n&7==j&7 (head==XCD)
    m0 = m * 128; n0 = n * 128;
  } else {
    m0 = blockIdx.y * 128; n0 = blockIdx.x * 128;
  }
  const int w = tid >> 6, l = tid & 63;
  const int wm = (w >> 1) * 64, wn = (w & 1) * 64;
  const int lr = l & 15, lg = l >> 4;
  f32x4 acc[4][4] = {};
  for (int k0 = 0; k0 < DMODEL; k0 += 64) {
    __syncthreads();
#pragma unroll
    for (int j = 0; j < 8; j++) {
      int c = w * 8 + j;          // 0..31; <16 -> A chunk, else B chunk
      int cc = c & 15;            // chunk within tile: rows cc*8..cc*8+7
      int r = cc * 8 + (l >> 3);
      int s = l & 7;              // 16B slot within 128B row
      const u16* src = (c < 16 ? A + (size_t)(m0 + r) * DMODEL
                               : Bt + (size_t)(n0 + r) * DMODEL)
                       + k0 + ((s ^ (r & 7)) * 8);
      gll16(src, (c < 16 ? As : Bs) + cc * 8 * 64);
    }
    asm volatile("s_waitcnt vmcnt(0)" ::: "memory");
    __syncthreads();
    s16x8 a[2][4], b[2][4];
#pragma unroll
    for (int hh = 0; hh < 2; hh++)
#pragma unroll
      for (int i = 0; i < 4; i++) {
        int ra = wm + i * 16 + lr;
        int oa = (ra * 128 + hh * 64 + lg * 16) ^ ((lr & 7) << 4);
        a[hh][i] = *reinterpret_cast<const s16x8*>((const char*)As + oa);
        int rb = wn + i * 16 + lr;
        int ob = (rb * 128 + hh * 64 + lg * 16) ^ ((lr & 7) << 4);
        b[hh][i] = *reinterpret_cast<const s16x8*>((const char*)Bs + ob);
      }
#pragma unroll
    for (int hh = 0; hh < 2; hh++)
#pragma unroll
      for (int i = 0; i < 4; i++)
#pragma unroll
        for (int j = 0; j < 4; j++)
          acc[i][j] = mfma16(a[hh][i], b[hh][j], acc[i][j]);
  }
  if (MODE == 0) {
    const int n = n0 >> 7;
    const int t = n >> 3, h = n & 7;
    u16* dst = outb + (size_t)(t * HEADS + h) * S_LEN * DH;
    if (t == 2 || t == 5) {
      // transposed: [d=128][s=2048]; pack 4 consecutive rows -> 8B store
#pragma unroll
      for (int i = 0; i < 4; i++)
#pragma unroll
        for (int j = 0; j < 4; j++) {
          int col = wn + j * 16 + lr;
          int row0 = m0 + wm + i * 16 + lg * 4;
          s16x4 p;
#pragma unroll
          for (int e = 0; e < 4; e++) p[e] = (short)f2b(acc[i][j][e]);
          *reinterpret_cast<s16x4*>(dst + (size_t)col * S_LEN + row0) = p;
        }
    } else {
      const float sc = (t == 0 || t == 3) ? SCALE : 1.0f;
#pragma unroll
      for (int i = 0; i < 4; i++)
#pragma unroll
        for (int j = 0; j < 4; j++)
#pragma unroll
          for (int e = 0; e < 4; e++) {
            int row = m0 + wm + i * 16 + lg * 4 + e;
            int col = wn + j * 16 + lr;
            dst[(size_t)row * DH + col] = f2b(acc[i][j][e] * sc);
          }
    }
  } else {
#pragma unroll
    for (int i = 0; i < 4; i++)
#pragma unroll
      for (int j = 0; j < 4; j++)
#pragma unroll
        for (int e = 0; e < 4; e++) {
          int row = m0 + wm + i * 16 + lg * 4 + e;
          int col = n0 + wn + j * 16 + lr;
          outf[(size_t)row * DMODEL + col] = acc[i][j][e];
        }
  }
}

// ---------------------------------------------------------------- diag correction
// per (qb, h): corr[row][col] = silu( (sigmoid(quku) masked col>row) @ vu )
// 1-D grid 128: h = bid&7 (XCD affinity), qb = bid>>3
__global__ void __launch_bounds__(256)
k_diag(const u16* __restrict__ qkvb, u16* __restrict__ corr) {
  __shared__ u16 PB[128][136];
  const int h = blockIdx.x & 7, qb = blockIdx.x >> 3;
  const int tid = threadIdx.x;
  const int w = tid >> 6, l = tid & 63;
  const int lr = l & 15, lg = l >> 4;
  const size_t hs = (size_t)S_LEN * DH;
  const u16* qu = qkvb + (size_t)(0 * HEADS + h) * hs;
  const u16* ku = qkvb + (size_t)(1 * HEADS + h) * hs;
  const u16* vuT = qkvb + (size_t)(2 * HEADS + h) * hs;  // [128][2048]
  const int rq = qb * 128 + w * 32;
  const u16* kub = ku + (size_t)qb * 128 * DH;
  f32x4 acc2[2][8] = {};
#pragma unroll
  for (int ks = 0; ks < 4; ks++) {
    s16x8 a0 = *reinterpret_cast<const s16x8*>(qu + (size_t)(rq + lr) * DH + ks * 32 + lg * 8);
    s16x8 a1 = *reinterpret_cast<const s16x8*>(qu + (size_t)(rq + 16 + lr) * DH + ks * 32 + lg * 8);
#pragma unroll
    for (int nf = 0; nf < 8; nf++) {
      s16x8 b = *reinterpret_cast<const s16x8*>(kub + (size_t)(nf * 16 + lr) * DH + ks * 32 + lg * 8);
      acc2[0][nf] = mfma16(a0, b, acc2[0][nf]);
      acc2[1][nf] = mfma16(a1, b, acc2[1][nf]);
    }
  }
#pragma unroll
  for (int mf = 0; mf < 2; mf++)
#pragma unroll
    for (int nf = 0; nf < 8; nf++)
#pragma unroll
      for (int e = 0; e < 4; e++) {
        int row = w * 32 + mf * 16 + lg * 4 + e;
        int col = nf * 16 + lr;
        float x = acc2[mf][nf][e];
        PB[row][col] = f2b((col > row) ? 1.f / (1.f + __expf(-x)) : 0.f);
        acc2[mf][nf][e] = 0.f;
      }
  // su = la @ vu  (PB rows are wave-private; vuT rows from global)
#pragma unroll
  for (int ks = 0; ks < 4; ks++) {
    s16x8 p0 = *reinterpret_cast<const s16x8*>(&PB[w * 32 + lr][ks * 32 + lg * 8]);
    s16x8 p1 = *reinterpret_cast<const s16x8*>(&PB[w * 32 + 16 + lr][ks * 32 + lg * 8]);
#pragma unroll
    for (int nf = 0; nf < 8; nf++) {
      s16x8 b = *reinterpret_cast<const s16x8*>(
          vuT + (size_t)(nf * 16 + lr) * S_LEN + qb * 128 + ks * 32 + lg * 8);
      acc2[0][nf] = mfma16(p0, b, acc2[0][nf]);
      acc2[1][nf] = mfma16(p1, b, acc2[1][nf]);
    }
  }
  u16* cp = corr + (size_t)(h * 16 + qb) * 16384;
#pragma unroll
  for (int mf = 0; mf < 2; mf++)
#pragma unroll
    for (int nf = 0; nf < 8; nf++)
#pragma unroll
      for (int e = 0; e < 4; e++) {
        int row = w * 32 + mf * 16 + lg * 4 + e;
        int col = nf * 16 + lr;
        float x = acc2[mf][nf][e];
        cp[row * 128 + col] = f2b(x / (1.f + __expf(-x)));
      }
}

// ---------------------------------------------------------------- attention phase 1
// 1-D grid 576: h = bid&7 (all 72 slots of a head pin to one XCD -> K/V/Q L2-hit),
// slot = bid>>3. 512 thr / 8 waves x 16 q-rows; <=2 key tiles; V^T via
// global_load_lds + XOR swizzle; K direct from L2; PB wave-private.
// Op writeout staged through VT (LDS) -> fully coalesced 16B/lane stores.
__global__ void __launch_bounds__(512, 4)
k_attn1(const u16* __restrict__ qkvb, const u16* __restrict__ corr,
        u16* __restrict__ opA, u16* __restrict__ opB, float* __restrict__ ml) {
  __shared__ u16 VT[128 * 128];   // linear [d=128][j=128], swizzled content
  __shared__ u16 PB[128][72];     // P halves, wave-private rows
  const int h = blockIdx.x & 7, slot = blockIdx.x >> 3;
  const int qb = SQB2[slot];
  const int t0 = (slot - PFX2[qb]) * 2;
  const int t1 = min(t0 + 2, qb + 1);
  const int tid = threadIdx.x;
  const int w = tid >> 6, l = tid & 63;
  const int lr = l & 15, lg = l >> 4;
  const size_t hs = (size_t)S_LEN * DH;
  const u16* qc = qkvb + (size_t)(3 * HEADS + h) * hs;
  const u16* kc = qkvb + (size_t)(4 * HEADS + h) * hs;
  const u16* vcT = qkvb + (size_t)(5 * HEADS + h) * hs;  // [128][2048]
  const int rq = qb * 128 + w * 16;

  f32x4 accO[8] = {};
  float mrun[4], lrun[4];
#pragma unroll
  for (int e = 0; e < 4; e++) { mrun[e] = -INFINITY; lrun[e] = 0.f; }

  // initial V stage for t0 (wave w covers d-rows w*16..w*16+15)
#pragma unroll
  for (int i = 0; i < 4; i++) {
    int r = w * 16 + i * 4 + (l >> 4);
    int s = l & 15;
    const u16* src = vcT + (size_t)r * S_LEN + t0 * 128 + ((s ^ (r & 7)) * 8);
    gll16(src, VT + (w * 16 + i * 4) * 128);
  }

  for (int t = t0; t < t1; t++) {
    const bool diag = (t == qb);
    const u16* kb = kc + (size_t)t * 128 * DH;
    f32x4 accS[8] = {};
#pragma unroll
    for (int ks = 0; ks < 4; ks++) {
      s16x8 a = *reinterpret_cast<const s16x8*>(
          qc + (size_t)(rq + lr) * DH + ks * 32 + lg * 8);
#pragma unroll
      for (int nf = 0; nf < 8; nf++) {
        s16x8 b = *reinterpret_cast<const s16x8*>(kb + (size_t)(nf * 16 + lr) * DH + ks * 32 + lg * 8);
        accS[nf] = mfma16(a, b, accS[nf]);
      }
    }
    if (diag) {
      const u16* cp = corr + (size_t)(h * 16 + qb) * 16384;
#pragma unroll
      for (int nf = 0; nf < 8; nf++)
#pragma unroll
        for (int e = 0; e < 4; e++) {
          int row = w * 16 + lg * 4 + e;
          int col = nf * 16 + lr;
          if (col > row) accS[nf][e] = -INFINITY;
          else accS[nf][e] -= b2f(cp[row * 128 + col]);
        }
    }
    float fac[4];
#pragma unroll
    for (int e = 0; e < 4; e++) {
      float mx = accS[0][e];
#pragma unroll
      for (int nf = 1; nf < 8; nf++) mx = fmaxf(mx, accS[nf][e]);
#pragma unroll
      for (int off = 1; off < 16; off <<= 1) mx = fmaxf(mx, __shfl_xor(mx, off, 64));
      float mnew = fmaxf(mrun[e], mx);
      float f = __expf(mrun[e] - mnew);
      float rs = 0.f;
#pragma unroll
      for (int nf = 0; nf < 8; nf++) {
        float p = __expf(accS[nf][e] - mnew);
        accS[nf][e] = p;
        rs += p;
      }
#pragma unroll
      for (int off = 1; off < 16; off <<= 1) rs += __shfl_xor(rs, off, 64);
      lrun[e] = lrun[e] * f + rs;
      mrun[e] = mnew;
      fac[e] = f;
    }
#pragma unroll
    for (int nf = 0; nf < 8; nf++)
#pragma unroll
      for (int e = 0; e < 4; e++) accO[nf][e] *= fac[e];
    asm volatile("s_waitcnt vmcnt(0)" ::: "memory");
    __syncthreads();  // all waves' V stages landed
    // PV in two 64-key halves; PB rows are wave-private
#pragma unroll
    for (int h2 = 0; h2 < 2; h2++) {
#pragma unroll
      for (int jj = 0; jj < 4; jj++)
#pragma unroll
        for (int e = 0; e < 4; e++)
          PB[w * 16 + lg * 4 + e][jj * 16 + lr] = f2b(accS[h2 * 4 + jj][e]);
#pragma unroll
      for (int ks2 = 0; ks2 < 2; ks2++) {
        s16x8 p = *reinterpret_cast<const s16x8*>(&PB[w * 16 + lr][ks2 * 32 + lg * 8]);
#pragma unroll
        for (int nf = 0; nf < 8; nf++) {
          int o = ((nf * 16 + lr) * 256 + h2 * 128 + ks2 * 64 + lg * 16) ^ ((lr & 7) << 4);
          s16x8 bv = *reinterpret_cast<const s16x8*>((const char*)VT + o);
          accO[nf] = mfma16(p, bv, accO[nf]);
        }
      }
    }
    __syncthreads();  // all waves done reading VT
    if (t + 1 < t1) {
#pragma unroll
      for (int i = 0; i < 4; i++) {
        int r = w * 16 + i * 4 + (l >> 4);
        int s = l & 15;
        const u16* src = vcT + (size_t)r * S_LEN + (t + 1) * 128 + ((s ^ (r & 7)) * 8);
        gll16(src, VT + (w * 16 + i * 4) * 128);
      }
    }
  }
  // ---- coalesced partial writeout: accO -> VT (LDS, wave-private rows) -> global
#pragma unroll
  for (int nf = 0; nf < 8; nf++)
#pragma unroll
    for (int e = 0; e < 4; e++)
      VT[(w * 16 + lg * 4 + e) * 128 + nf * 16 + lr] = f2b(accO[nf][e]);
  __syncthreads();
  const int gs = h * 72 + slot;
  u16* op = gs < 384 ? opA + (size_t)gs * 16384 : opB + (size_t)(gs - 384) * 16384;
#pragma unroll
  for (int i = 0; i < 4; i++)
    reinterpret_cast<s16x8*>(op)[tid + i * 512] =
        reinterpret_cast<const s16x8*>(VT)[tid + i * 512];
  if (lr == 0) {
    float* mlp = ml + (size_t)gs * 256;
#pragma unroll
    for (int e = 0; e < 4; e++) {
      int row = w * 16 + lg * 4 + e;
      mlp[row] = mrun[e];
      mlp[128 + row] = lrun[e];
    }
  }
}

// ---------------------------------------------------------------- phase 2 merge
// 1-D grid 128: h = bid&7 (same XCD as producer slots), qb = bid>>3
__global__ void __launch_bounds__(256)
k_attn2(const u16* __restrict__ opA, const u16* __restrict__ opB,
        const float* __restrict__ ml, u16* __restrict__ obuf) {
  const int h = blockIdx.x & 7, qb = blockIdx.x >> 3;
  const int nc = (qb >> 1) + 1;
  const int s0 = h * 72 + PFX2[qb];
  const int row = threadIdx.x >> 1, c0 = (threadIdx.x & 1) * 64;
  float mg = -INFINITY;
  for (int c = 0; c < nc; c++) mg = fmaxf(mg, ml[(size_t)(s0 + c) * 256 + row]);
  float acc[64];
#pragma unroll
  for (int k = 0; k < 64; k++) acc[k] = 0.f;
  float lsum = 0.f;
  for (int c = 0; c < nc; c++) {
    int gs = s0 + c;
    const float* mlp = ml + (size_t)gs * 256;
    float f = __expf(mlp[row] - mg);
    lsum += f * mlp[128 + row];
    const u16* p = (gs < 384 ? opA + (size_t)gs * 16384
                             : opB + (size_t)(gs - 384) * 16384) + row * 128 + c0;
#pragma unroll
    for (int k = 0; k < 8; k++) {
      s16x8 v = *reinterpret_cast<const s16x8*>(p + k * 8);
#pragma unroll
      for (int j = 0; j < 8; j++) acc[k * 8 + j] += f * b2f((u16)v[j]);
    }
  }
  float inv = 1.f / lsum;
  u16* dst = obuf + (size_t)(qb * 128 + row) * DMODEL + h * DH + c0;
#pragma unroll
  for (int k = 0; k < 8; k++) {
    s16x8 o;
#pragma unroll
    for (int j = 0; j < 8; j++) o[j] = (short)f2b(acc[k * 8 + j] * inv);
    *reinterpret_cast<s16x8*>(dst + k * 8) = o;
  }
}

// ---------------------------------------------------------------- launcher
extern "C" void kernel_launch(void* const* d_in, const int* in_sizes, int n_in,
                              void* d_out, int out_size, void* d_ws, size_t ws_size,
                              hipStream_t stream) {
  (void)in_sizes; (void)n_in; (void)out_size; (void)ws_size;
  const float* x = (const float*)d_in[0];
  const float* wqkv = (const float*)d_in[1];
  const float* wout = (const float*)d_in[2];
  char* ws = (char*)d_ws;
  u16* xb    = (u16*)(ws + 0);          // 4 MB; dead after gemm0
  u16* corrb = (u16*)(ws + 0);          // k_diag output (reuses xb)
  u16* wqT   = (u16*)(ws + 4194304);    // 12.58 MB; dead after gemm0
  u16* opB   = (u16*)(ws + 4194304);    // attn partials slots 384..575 (6.29 MB)
  float* mlb = (float*)(ws + 10485760); // 576*256*4 = 0.59 MB
  u16* woT   = (u16*)(ws + 16777216);   // 2 MB
  u16* qkvb  = (u16*)(ws + 18874368);   // 24 MB: [qu|ku|vuT|qc|kc|vcT] 4 MB each
  u16* opA   = (u16*)(ws + 18874368);   // attn partials slots 0..383 (12 MB,
                                        //   overwrites qu/ku/vuT after k_diag)
  u16* obuf  = (u16*)(ws + 44040192);   // 4 MB
  float* out = (float*)d_out;

  k_cast<<<2048, 256, 0, stream>>>(x, xb);
  k_transpose<<<dim3(192, 32), dim3(32, 8), 0, stream>>>(wqkv, wqT, DMODEL, NQKV);
  k_transpose<<<dim3(32, 32), dim3(32, 8), 0, stream>>>(wout, woT, DMODEL, DMODEL);
  k_gemm2<0><<<768, 256, 0, stream>>>(xb, wqT, qkvb, nullptr);
  k_diag<<<128, 256, 0, stream>>>(qkvb, corrb);
  k_attn1<<<576, 512, 0, stream>>>(qkvb, corrb, opA, opB, mlb);
  k_attn2<<<128, 256, 0, stream>>>(opA, opB, mlb, obuf);
  k_gemm2<1><<<dim3(8, 16), 256, 0, stream>>>(obuf, woT, nullptr, out);
}

// Round 6
// 180.143 us; speedup vs baseline: 1.1314x; 1.1003x over previous
//
#include <hip/hip_runtime.h>

#define S_LEN 2048
#define DMODEL 1024
#define HEADS 8
#define DH 128
#define NQKV 6144
#define SCALE 0.08838834764831845f

typedef unsigned short u16;
typedef short s16x8 __attribute__((ext_vector_type(8)));
typedef short s16x4 __attribute__((ext_vector_type(4)));
typedef float f32x4 __attribute__((ext_vector_type(4)));

static __device__ __forceinline__ f32x4 mfma16(s16x8 a, s16x8 b, f32x4 c) {
  return __builtin_amdgcn_mfma_f32_16x16x32_bf16(a, b, c, 0, 0, 0);
}
static __device__ __forceinline__ u16 f2b(float f) {
  union { float f; unsigned u; } v; v.f = f;
  unsigned r = v.u + 0x7fffu + ((v.u >> 16) & 1u);
  return (u16)(r >> 16);
}
static __device__ __forceinline__ float b2f(u16 s) {
  union { unsigned u; float f; } v; v.u = ((unsigned)s) << 16;
  return v.f;
}
// async global->LDS, 16B per lane; lds dest = uniform base + lane*16
static __device__ __forceinline__ void gll16(const u16* g, u16* l) {
  __builtin_amdgcn_global_load_lds(
      (const __attribute__((address_space(1))) unsigned int*)g,
      (__attribute__((address_space(3))) unsigned int*)l, 16, 0, 0);
}

// chunk = 2 key tiles
static __device__ const int PFX2[16] = {0,1,2,4,6,9,12,16,20,25,30,36,42,49,56,64};
static __device__ const int SQB2[72] = {
  0,1,2,2,3,3,4,4,4,5,5,5,6,6,6,6,7,7,7,7,
  8,8,8,8,8,9,9,9,9,9,10,10,10,10,10,10,11,11,11,11,11,11,
  12,12,12,12,12,12,12,13,13,13,13,13,13,13,
  14,14,14,14,14,14,14,14,15,15,15,15,15,15,15,15};

// ---------------------------------------------------------------- cast x -> bf16
__global__ void k_cast(const float* __restrict__ in, u16* __restrict__ out) {
  int i = blockIdx.x * 256 + threadIdx.x;
  float4 v = reinterpret_cast<const float4*>(in)[i];
  s16x4 o;
  o[0] = (short)f2b(v.x); o[1] = (short)f2b(v.y);
  o[2] = (short)f2b(v.z); o[3] = (short)f2b(v.w);
  reinterpret_cast<s16x4*>(out)[i] = o;
}

// ------------------------------------------- transpose+cast: out[c][r] = in[r][c]
__global__ void k_transpose(const float* __restrict__ in, u16* __restrict__ out,
                            int R, int C) {
  __shared__ float tile[32][33];
  int c0 = blockIdx.x * 32, r0 = blockIdx.y * 32;
#pragma unroll
  for (int k = 0; k < 4; k++)
    tile[threadIdx.y + k * 8][threadIdx.x] =
        in[(size_t)(r0 + threadIdx.y + k * 8) * C + c0 + threadIdx.x];
  __syncthreads();
#pragma unroll
  for (int k = 0; k < 4; k++)
    out[(size_t)(c0 + threadIdx.y + k * 8) * R + r0 + threadIdx.x] =
        f2b(tile[threadIdx.x][threadIdx.y + k * 8]);
}

// ---------------------------------------------------------------- GEMM (m97-style)
// C[M,N] = A[M,K] @ Bt[N,K]^T, K=1024, 128x128 tile, BK=64, global_load_lds w16,
// XOR-swizzled LDS (linear [128][64], byte ^= ((row&7)<<4)).
// MODE 0: 1-D grid 768; XCD x computes n-tiles with n&7==x (head x -> XCD x).
// MODE 1: 2-D grid, f32 out [M][1024].
template <int MODE>
__global__ void __launch_bounds__(256, 3)
k_gemm2(const u16* __restrict__ A, const u16* __restrict__ Bt,
        u16* __restrict__ outb, float* __restrict__ outf) {
  __shared__ u16 As[128 * 64];
  __shared__ u16 Bs[128 * 64];
  const int tid = threadIdx.x;
  int m0, n0;
  if (MODE == 0) {
    int m = blockIdx.x / 48, j = blockIdx.x % 48;
    int n = (j & 7) + 8 * (j >> 3);  // XCD (j&7) owns all n with n&7==j&7 (head==XCD)
    m0 = m * 128; n0 = n * 128;
  } else {
    m0 = blockIdx.y * 128; n0 = blockIdx.x * 128;
  }
  const int w = tid >> 6, l = tid & 63;
  const int wm = (w >> 1) * 64, wn = (w & 1) * 64;
  const int lr = l & 15, lg = l >> 4;
  f32x4 acc[4][4] = {};
  for (int k0 = 0; k0 < DMODEL; k0 += 64) {
    __syncthreads();
#pragma unroll
    for (int j = 0; j < 8; j++) {
      int c = w * 8 + j;          // 0..31; <16 -> A chunk, else B chunk
      int cc = c & 15;            // chunk within tile: rows cc*8..cc*8+7
      int r = cc * 8 + (l >> 3);
      int s = l & 7;              // 16B slot within 128B row
      const u16* src = (c < 16 ? A + (size_t)(m0 + r) * DMODEL
                               : Bt + (size_t)(n0 + r) * DMODEL)
                       + k0 + ((s ^ (r & 7)) * 8);
      gll16(src, (c < 16 ? As : Bs) + cc * 8 * 64);
    }
    asm volatile("s_waitcnt vmcnt(0)" ::: "memory");
    __syncthreads();
    s16x8 a[2][4], b[2][4];
#pragma unroll
    for (int hh = 0; hh < 2; hh++)
#pragma unroll
      for (int i = 0; i < 4; i++) {
        int ra = wm + i * 16 + lr;
        int oa = (ra * 128 + hh * 64 + lg * 16) ^ ((lr & 7) << 4);
        a[hh][i] = *reinterpret_cast<const s16x8*>((const char*)As + oa);
        int rb = wn + i * 16 + lr;
        int ob = (rb * 128 + hh * 64 + lg * 16) ^ ((lr & 7) << 4);
        b[hh][i] = *reinterpret_cast<const s16x8*>((const char*)Bs + ob);
      }
#pragma unroll
    for (int hh = 0; hh < 2; hh++)
#pragma unroll
      for (int i = 0; i < 4; i++)
#pragma unroll
        for (int j = 0; j < 4; j++)
          acc[i][j] = mfma16(a[hh][i], b[hh][j], acc[i][j]);
  }
  if (MODE == 0) {
    const int n = n0 >> 7;
    const int t = n >> 3, h = n & 7;
    u16* dst = outb + (size_t)(t * HEADS + h) * S_LEN * DH;
    if (t == 2 || t == 5) {
      // transposed: [d=128][s=2048]; pack 4 consecutive rows -> 8B store
#pragma unroll
      for (int i = 0; i < 4; i++)
#pragma unroll
        for (int j = 0; j < 4; j++) {
          int col = wn + j * 16 + lr;
          int row0 = m0 + wm + i * 16 + lg * 4;
          s16x4 p;
#pragma unroll
          for (int e = 0; e < 4; e++) p[e] = (short)f2b(acc[i][j][e]);
          *reinterpret_cast<s16x4*>(dst + (size_t)col * S_LEN + row0) = p;
        }
    } else {
      const float sc = (t == 0 || t == 3) ? SCALE : 1.0f;
#pragma unroll
      for (int i = 0; i < 4; i++)
#pragma unroll
        for (int j = 0; j < 4; j++)
#pragma unroll
          for (int e = 0; e < 4; e++) {
            int row = m0 + wm + i * 16 + lg * 4 + e;
            int col = wn + j * 16 + lr;
            dst[(size_t)row * DH + col] = f2b(acc[i][j][e] * sc);
          }
    }
  } else {
#pragma unroll
    for (int i = 0; i < 4; i++)
#pragma unroll
      for (int j = 0; j < 4; j++)
#pragma unroll
        for (int e = 0; e < 4; e++) {
          int row = m0 + wm + i * 16 + lg * 4 + e;
          int col = n0 + wn + j * 16 + lr;
          outf[(size_t)row * DMODEL + col] = acc[i][j][e];
        }
  }
}

// ---------------------------------------------------------------- diag correction
// per (qb, h): corr[row][col] = silu( (sigmoid(quku) masked col>row) @ vu )
// 1-D grid 128: h = bid&7 (XCD affinity), qb = bid>>3
__global__ void __launch_bounds__(256)
k_diag(const u16* __restrict__ qkvb, u16* __restrict__ corr) {
  __shared__ u16 PB[128][136];
  const int h = blockIdx.x & 7, qb = blockIdx.x >> 3;
  const int tid = threadIdx.x;
  const int w = tid >> 6, l = tid & 63;
  const int lr = l & 15, lg = l >> 4;
  const size_t hs = (size_t)S_LEN * DH;
  const u16* qu = qkvb + (size_t)(0 * HEADS + h) * hs;
  const u16* ku = qkvb + (size_t)(1 * HEADS + h) * hs;
  const u16* vuT = qkvb + (size_t)(2 * HEADS + h) * hs;  // [128][2048]
  const int rq = qb * 128 + w * 32;
  const u16* kub = ku + (size_t)qb * 128 * DH;
  f32x4 acc2[2][8] = {};
#pragma unroll
  for (int ks = 0; ks < 4; ks++) {
    s16x8 a0 = *reinterpret_cast<const s16x8*>(qu + (size_t)(rq + lr) * DH + ks * 32 + lg * 8);
    s16x8 a1 = *reinterpret_cast<const s16x8*>(qu + (size_t)(rq + 16 + lr) * DH + ks * 32 + lg * 8);
#pragma unroll
    for (int nf = 0; nf < 8; nf++) {
      s16x8 b = *reinterpret_cast<const s16x8*>(kub + (size_t)(nf * 16 + lr) * DH + ks * 32 + lg * 8);
      acc2[0][nf] = mfma16(a0, b, acc2[0][nf]);
      acc2[1][nf] = mfma16(a1, b, acc2[1][nf]);
    }
  }
#pragma unroll
  for (int mf = 0; mf < 2; mf++)
#pragma unroll
    for (int nf = 0; nf < 8; nf++)
#pragma unroll
      for (int e = 0; e < 4; e++) {
        int row = w * 32 + mf * 16 + lg * 4 + e;
        int col = nf * 16 + lr;
        float x = acc2[mf][nf][e];
        PB[row][col] = f2b((col > row) ? 1.f / (1.f + __expf(-x)) : 0.f);
        acc2[mf][nf][e] = 0.f;
      }
  // su = la @ vu  (PB rows are wave-private; vuT rows from global)
#pragma unroll
  for (int ks = 0; ks < 4; ks++) {
    s16x8 p0 = *reinterpret_cast<const s16x8*>(&PB[w * 32 + lr][ks * 32 + lg * 8]);
    s16x8 p1 = *reinterpret_cast<const s16x8*>(&PB[w * 32 + 16 + lr][ks * 32 + lg * 8]);
#pragma unroll
    for (int nf = 0; nf < 8; nf++) {
      s16x8 b = *reinterpret_cast<const s16x8*>(
          vuT + (size_t)(nf * 16 + lr) * S_LEN + qb * 128 + ks * 32 + lg * 8);
      acc2[0][nf] = mfma16(p0, b, acc2[0][nf]);
      acc2[1][nf] = mfma16(p1, b, acc2[1][nf]);
    }
  }
  u16* cp = corr + (size_t)(h * 16 + qb) * 16384;
#pragma unroll
  for (int mf = 0; mf < 2; mf++)
#pragma unroll
    for (int nf = 0; nf < 8; nf++)
#pragma unroll
      for (int e = 0; e < 4; e++) {
        int row = w * 32 + mf * 16 + lg * 4 + e;
        int col = nf * 16 + lr;
        float x = acc2[mf][nf][e];
        cp[row * 128 + col] = f2b(x / (1.f + __expf(-x)));
      }
}

// ---------------------------------------------------------------- attention phase 1
// 1-D grid 576: h = bid&7 (XCD pinning), slot = bid>>3. 512 thr / 8 waves x 16
// q-rows; <=2 key tiles. K AND V staged through ONE shared 32KB LDS buffer via
// global_load_lds + XOR swizzle (stage K -> QK^T -> softmax -> bar -> stage V ->
// PV -> bar). K read once per block (was 8x, per-wave, latency-serialized).
__global__ void __launch_bounds__(512, 4)
k_attn1(const u16* __restrict__ qkvb, const u16* __restrict__ corr,
        u16* __restrict__ opA, u16* __restrict__ opB, float* __restrict__ ml) {
  __shared__ u16 KV[128 * 128];   // K tile, then V^T tile (swizzled content)
  __shared__ u16 PB[128][72];     // P halves, wave-private rows
  const int h = blockIdx.x & 7, slot = blockIdx.x >> 3;
  const int qb = SQB2[slot];
  const int t0 = (slot - PFX2[qb]) * 2;
  const int t1 = min(t0 + 2, qb + 1);
  const int tid = threadIdx.x;
  const int w = tid >> 6, l = tid & 63;
  const int lr = l & 15, lg = l >> 4;
  const size_t hs = (size_t)S_LEN * DH;
  const u16* qc = qkvb + (size_t)(3 * HEADS + h) * hs;
  const u16* kc = qkvb + (size_t)(4 * HEADS + h) * hs;
  const u16* vcT = qkvb + (size_t)(5 * HEADS + h) * hs;  // [128][2048]
  const int rq = qb * 128 + w * 16;

  f32x4 accO[8] = {};
  float mrun[4], lrun[4];
#pragma unroll
  for (int e = 0; e < 4; e++) { mrun[e] = -INFINITY; lrun[e] = 0.f; }

  // prologue: stage K(t0); wave w covers rows w*16..w*16+15
  {
    const u16* kb = kc + (size_t)t0 * 128 * DH;
#pragma unroll
    for (int i = 0; i < 4; i++) {
      int r = w * 16 + i * 4 + (l >> 4);
      int s = l & 15;
      gll16(kb + r * DH + ((s ^ (r & 7)) * 8), KV + (w * 16 + i * 4) * 128);
    }
    asm volatile("s_waitcnt vmcnt(0)" ::: "memory");
    __syncthreads();
  }

  for (int t = t0; t < t1; t++) {
    const bool diag = (t == qb);
    // ---- QK^T from LDS (swizzled ds_read_b128)
    f32x4 accS[8] = {};
#pragma unroll
    for (int ks = 0; ks < 4; ks++) {
      s16x8 a = *reinterpret_cast<const s16x8*>(
          qc + (size_t)(rq + lr) * DH + ks * 32 + lg * 8);
#pragma unroll
      for (int nf = 0; nf < 8; nf++) {
        int o = ((nf * 16 + lr) * 256 + ks * 64 + lg * 16) ^ ((lr & 7) << 4);
        s16x8 b = *reinterpret_cast<const s16x8*>((const char*)KV + o);
        accS[nf] = mfma16(a, b, accS[nf]);
      }
    }
    if (diag) {
      const u16* cp = corr + (size_t)(h * 16 + qb) * 16384;
#pragma unroll
      for (int nf = 0; nf < 8; nf++)
#pragma unroll
        for (int e = 0; e < 4; e++) {
          int row = w * 16 + lg * 4 + e;
          int col = nf * 16 + lr;
          if (col > row) accS[nf][e] = -INFINITY;
          else accS[nf][e] -= b2f(cp[row * 128 + col]);
        }
    }
    // ---- online softmax
    float fac[4];
#pragma unroll
    for (int e = 0; e < 4; e++) {
      float mx = accS[0][e];
#pragma unroll
      for (int nf = 1; nf < 8; nf++) mx = fmaxf(mx, accS[nf][e]);
#pragma unroll
      for (int off = 1; off < 16; off <<= 1) mx = fmaxf(mx, __shfl_xor(mx, off, 64));
      float mnew = fmaxf(mrun[e], mx);
      float f = __expf(mrun[e] - mnew);
      float rs = 0.f;
#pragma unroll
      for (int nf = 0; nf < 8; nf++) {
        float p = __expf(accS[nf][e] - mnew);
        accS[nf][e] = p;
        rs += p;
      }
#pragma unroll
      for (int off = 1; off < 16; off <<= 1) rs += __shfl_xor(rs, off, 64);
      lrun[e] = lrun[e] * f + rs;
      mrun[e] = mnew;
      fac[e] = f;
    }
#pragma unroll
    for (int nf = 0; nf < 8; nf++)
#pragma unroll
      for (int e = 0; e < 4; e++) accO[nf][e] *= fac[e];
    __syncthreads();  // all waves done reading K from KV
    // ---- stage V^T(t) into KV (overwrites K)
#pragma unroll
    for (int i = 0; i < 4; i++) {
      int r = w * 16 + i * 4 + (l >> 4);
      int s = l & 15;
      gll16(vcT + (size_t)r * S_LEN + t * 128 + ((s ^ (r & 7)) * 8),
            KV + (w * 16 + i * 4) * 128);
    }
    asm volatile("s_waitcnt vmcnt(0)" ::: "memory");
    __syncthreads();
    // ---- PV in two 64-key halves; PB rows wave-private
#pragma unroll
    for (int h2 = 0; h2 < 2; h2++) {
#pragma unroll
      for (int jj = 0; jj < 4; jj++)
#pragma unroll
        for (int e = 0; e < 4; e++)
          PB[w * 16 + lg * 4 + e][jj * 16 + lr] = f2b(accS[h2 * 4 + jj][e]);
#pragma unroll
      for (int ks2 = 0; ks2 < 2; ks2++) {
        s16x8 p = *reinterpret_cast<const s16x8*>(&PB[w * 16 + lr][ks2 * 32 + lg * 8]);
#pragma unroll
        for (int nf = 0; nf < 8; nf++) {
          int o = ((nf * 16 + lr) * 256 + h2 * 128 + ks2 * 64 + lg * 16) ^ ((lr & 7) << 4);
          s16x8 bv = *reinterpret_cast<const s16x8*>((const char*)KV + o);
          accO[nf] = mfma16(p, bv, accO[nf]);
        }
      }
    }
    __syncthreads();  // all waves done reading V from KV
    if (t + 1 < t1) {
      const u16* kb = kc + (size_t)(t + 1) * 128 * DH;
#pragma unroll
      for (int i = 0; i < 4; i++) {
        int r = w * 16 + i * 4 + (l >> 4);
        int s = l & 15;
        gll16(kb + r * DH + ((s ^ (r & 7)) * 8), KV + (w * 16 + i * 4) * 128);
      }
      asm volatile("s_waitcnt vmcnt(0)" ::: "memory");
      __syncthreads();
    }
  }
  // ---- coalesced partial writeout: accO -> KV (LDS) -> global
#pragma unroll
  for (int nf = 0; nf < 8; nf++)
#pragma unroll
    for (int e = 0; e < 4; e++)
      KV[(w * 16 + lg * 4 + e) * 128 + nf * 16 + lr] = f2b(accO[nf][e]);
  __syncthreads();
  const int gs = h * 72 + slot;
  u16* op = gs < 384 ? opA + (size_t)gs * 16384 : opB + (size_t)(gs - 384) * 16384;
#pragma unroll
  for (int i = 0; i < 4; i++)
    reinterpret_cast<s16x8*>(op)[tid + i * 512] =
        reinterpret_cast<const s16x8*>(KV)[tid + i * 512];
  if (lr == 0) {
    float* mlp = ml + (size_t)gs * 256;
#pragma unroll
    for (int e = 0; e < 4; e++) {
      int row = w * 16 + lg * 4 + e;
      mlp[row] = mrun[e];
      mlp[128 + row] = lrun[e];
    }
  }
}

// ---------------------------------------------------------------- phase 2 merge
// 1-D grid 128: h = bid&7 (same XCD as producer slots), qb = bid>>3
__global__ void __launch_bounds__(256)
k_attn2(const u16* __restrict__ opA, const u16* __restrict__ opB,
        const float* __restrict__ ml, u16* __restrict__ obuf) {
  const int h = blockIdx.x & 7, qb = blockIdx.x >> 3;
  const int nc = (qb >> 1) + 1;
  const int s0 = h * 72 + PFX2[qb];
  const int row = threadIdx.x >> 1, c0 = (threadIdx.x & 1) * 64;
  float mg = -INFINITY;
  for (int c = 0; c < nc; c++) mg = fmaxf(mg, ml[(size_t)(s0 + c) * 256 + row]);
  float acc[64];
#pragma unroll
  for (int k = 0; k < 64; k++) acc[k] = 0.f;
  float lsum = 0.f;
  for (int c = 0; c < nc; c++) {
    int gs = s0 + c;
    const float* mlp = ml + (size_t)gs * 256;
    float f = __expf(mlp[row] - mg);
    lsum += f * mlp[128 + row];
    const u16* p = (gs < 384 ? opA + (size_t)gs * 16384
                             : opB + (size_t)(gs - 384) * 16384) + row * 128 + c0;
#pragma unroll
    for (int k = 0; k < 8; k++) {
      s16x8 v = *reinterpret_cast<const s16x8*>(p + k * 8);
#pragma unroll
      for (int j = 0; j < 8; j++) acc[k * 8 + j] += f * b2f((u16)v[j]);
    }
  }
  float inv = 1.f / lsum;
  u16* dst = obuf + (size_t)(qb * 128 + row) * DMODEL + h * DH + c0;
#pragma unroll
  for (int k = 0; k < 8; k++) {
    s16x8 o;
#pragma unroll
    for (int j = 0; j < 8; j++) o[j] = (short)f2b(acc[k * 8 + j] * inv);
    *reinterpret_cast<s16x8*>(dst + k * 8) = o;
  }
}

// ---------------------------------------------------------------- launcher
extern "C" void kernel_launch(void* const* d_in, const int* in_sizes, int n_in,
                              void* d_out, int out_size, void* d_ws, size_t ws_size,
                              hipStream_t stream) {
  (void)in_sizes; (void)n_in; (void)out_size; (void)ws_size;
  const float* x = (const float*)d_in[0];
  const float* wqkv = (const float*)d_in[1];
  const float* wout = (const float*)d_in[2];
  char* ws = (char*)d_ws;
  u16* xb    = (u16*)(ws + 0);          // 4 MB; dead after gemm0
  u16* corrb = (u16*)(ws + 0);          // k_diag output (reuses xb)
  u16* wqT   = (u16*)(ws + 4194304);    // 12.58 MB; dead after gemm0
  u16* opB   = (u16*)(ws + 4194304);    // attn partials slots 384..575 (6.29 MB)
  float* mlb = (float*)(ws + 10485760); // 576*256*4 = 0.59 MB
  u16* woT   = (u16*)(ws + 16777216);   // 2 MB
  u16* qkvb  = (u16*)(ws + 18874368);   // 24 MB: [qu|ku|vuT|qc|kc|vcT] 4 MB each
  u16* opA   = (u16*)(ws + 18874368);   // attn partials slots 0..383 (12 MB,
                                        //   overwrites qu/ku/vuT after k_diag)
  u16* obuf  = (u16*)(ws + 44040192);   // 4 MB
  float* out = (float*)d_out;

  k_cast<<<2048, 256, 0, stream>>>(x, xb);
  k_transpose<<<dim3(192, 32), dim3(32, 8), 0, stream>>>(wqkv, wqT, DMODEL, NQKV);
  k_transpose<<<dim3(32, 32), dim3(32, 8), 0, stream>>>(wout, woT, DMODEL, DMODEL);
  k_gemm2<0><<<768, 256, 0, stream>>>(xb, wqT, qkvb, nullptr);
  k_diag<<<128, 256, 0, stream>>>(qkvb, corrb);
  k_attn1<<<576, 512, 0, stream>>>(qkvb, corrb, opA, opB, mlb);
  k_attn2<<<128, 256, 0, stream>>>(opA, opB, mlb, obuf);
  k_gemm2<1><<<dim3(8, 16), 256, 0, stream>>>(obuf, woT, nullptr, out);
}

// Round 7
// 155.967 us; speedup vs baseline: 1.3068x; 1.1550x over previous
//
#include <hip/hip_runtime.h>

#define S_LEN 2048
#define DMODEL 1024
#define HEADS 8
#define DH 128
#define NQKV 6144
#define SCALE 0.08838834764831845f

typedef unsigned short u16;
typedef short s16x8 __attribute__((ext_vector_type(8)));
typedef short s16x4 __attribute__((ext_vector_type(4)));
typedef float f32x4 __attribute__((ext_vector_type(4)));

static __device__ __forceinline__ f32x4 mfma16(s16x8 a, s16x8 b, f32x4 c) {
  return __builtin_amdgcn_mfma_f32_16x16x32_bf16(a, b, c, 0, 0, 0);
}
static __device__ __forceinline__ u16 f2b(float f) {
  union { float f; unsigned u; } v; v.f = f;
  unsigned r = v.u + 0x7fffu + ((v.u >> 16) & 1u);
  return (u16)(r >> 16);
}
static __device__ __forceinline__ float b2f(u16 s) {
  union { unsigned u; float f; } v; v.u = ((unsigned)s) << 16;
  return v.f;
}
// async global->LDS, 16B per lane; lds dest = uniform base + lane*16
static __device__ __forceinline__ void gll16(const u16* g, u16* l) {
  __builtin_amdgcn_global_load_lds(
      (const __attribute__((address_space(1))) unsigned int*)g,
      (__attribute__((address_space(3))) unsigned int*)l, 16, 0, 0);
}

// chunk = 2 key tiles
static __device__ const int PFX2[16] = {0,1,2,4,6,9,12,16,20,25,30,36,42,49,56,64};
static __device__ const int SQB2[72] = {
  0,1,2,2,3,3,4,4,4,5,5,5,6,6,6,6,7,7,7,7,
  8,8,8,8,8,9,9,9,9,9,10,10,10,10,10,10,11,11,11,11,11,11,
  12,12,12,12,12,12,12,13,13,13,13,13,13,13,
  14,14,14,14,14,14,14,14,15,15,15,15,15,15,15,15};

// ---------------------------------------------------------------- cast x -> bf16
__global__ void k_cast(const float* __restrict__ in, u16* __restrict__ out) {
  int i = blockIdx.x * 256 + threadIdx.x;
  float4 v = reinterpret_cast<const float4*>(in)[i];
  s16x4 o;
  o[0] = (short)f2b(v.x); o[1] = (short)f2b(v.y);
  o[2] = (short)f2b(v.z); o[3] = (short)f2b(v.w);
  reinterpret_cast<s16x4*>(out)[i] = o;
}

// ------------------------------------------- transpose+cast: out[c][r] = in[r][c]
__global__ void k_transpose(const float* __restrict__ in, u16* __restrict__ out,
                            int R, int C) {
  __shared__ float tile[32][33];
  int c0 = blockIdx.x * 32, r0 = blockIdx.y * 32;
#pragma unroll
  for (int k = 0; k < 4; k++)
    tile[threadIdx.y + k * 8][threadIdx.x] =
        in[(size_t)(r0 + threadIdx.y + k * 8) * C + c0 + threadIdx.x];
  __syncthreads();
#pragma unroll
  for (int k = 0; k < 4; k++)
    out[(size_t)(c0 + threadIdx.y + k * 8) * R + r0 + threadIdx.x] =
        f2b(tile[threadIdx.x][threadIdx.y + k * 8]);
}

// ---------------------------------------------------------------- GEMM (m97-style)
// C[M,N] = A[M,K] @ Bt[N,K]^T, K=1024, 128x128 tile, BK=64, global_load_lds w16,
// XOR-swizzled LDS (linear [128][64], byte ^= ((row&7)<<4)).
// MODE 0: 1-D grid 768; XCD x computes n-tiles with n&7==x (head x -> XCD x).
// MODE 1: 2-D grid, f32 out [M][1024].
template <int MODE>
__global__ void __launch_bounds__(256, 3)
k_gemm2(const u16* __restrict__ A, const u16* __restrict__ Bt,
        u16* __restrict__ outb, float* __restrict__ outf) {
  __shared__ u16 As[128 * 64];
  __shared__ u16 Bs[128 * 64];
  const int tid = threadIdx.x;
  int m0, n0;
  if (MODE == 0) {
    int m = blockIdx.x / 48, j = blockIdx.x % 48;
    int n = (j & 7) + 8 * (j >> 3);  // XCD (j&7) owns all n with n&7==j&7 (head==XCD)
    m0 = m * 128; n0 = n * 128;
  } else {
    m0 = blockIdx.y * 128; n0 = blockIdx.x * 128;
  }
  const int w = tid >> 6, l = tid & 63;
  const int wm = (w >> 1) * 64, wn = (w & 1) * 64;
  const int lr = l & 15, lg = l >> 4;
  f32x4 acc[4][4] = {};
  for (int k0 = 0; k0 < DMODEL; k0 += 64) {
    __syncthreads();
#pragma unroll
    for (int j = 0; j < 8; j++) {
      int c = w * 8 + j;          // 0..31; <16 -> A chunk, else B chunk
      int cc = c & 15;            // chunk within tile: rows cc*8..cc*8+7
      int r = cc * 8 + (l >> 3);
      int s = l & 7;              // 16B slot within 128B row
      const u16* src = (c < 16 ? A + (size_t)(m0 + r) * DMODEL
                               : Bt + (size_t)(n0 + r) * DMODEL)
                       + k0 + ((s ^ (r & 7)) * 8);
      gll16(src, (c < 16 ? As : Bs) + cc * 8 * 64);
    }
    asm volatile("s_waitcnt vmcnt(0)" ::: "memory");
    __syncthreads();
    s16x8 a[2][4], b[2][4];
#pragma unroll
    for (int hh = 0; hh < 2; hh++)
#pragma unroll
      for (int i = 0; i < 4; i++) {
        int ra = wm + i * 16 + lr;
        int oa = (ra * 128 + hh * 64 + lg * 16) ^ ((lr & 7) << 4);
        a[hh][i] = *reinterpret_cast<const s16x8*>((const char*)As + oa);
        int rb = wn + i * 16 + lr;
        int ob = (rb * 128 + hh * 64 + lg * 16) ^ ((lr & 7) << 4);
        b[hh][i] = *reinterpret_cast<const s16x8*>((const char*)Bs + ob);
      }
#pragma unroll
    for (int hh = 0; hh < 2; hh++)
#pragma unroll
      for (int i = 0; i < 4; i++)
#pragma unroll
        for (int j = 0; j < 4; j++)
          acc[i][j] = mfma16(a[hh][i], b[hh][j], acc[i][j]);
  }
  if (MODE == 0) {
    const int n = n0 >> 7;
    const int t = n >> 3, h = n & 7;
    u16* dst = outb + (size_t)(t * HEADS + h) * S_LEN * DH;
    if (t == 2 || t == 5) {
      // transposed: [d=128][s=2048]; pack 4 consecutive rows -> 8B store
#pragma unroll
      for (int i = 0; i < 4; i++)
#pragma unroll
        for (int j = 0; j < 4; j++) {
          int col = wn + j * 16 + lr;
          int row0 = m0 + wm + i * 16 + lg * 4;
          s16x4 p;
#pragma unroll
          for (int e = 0; e < 4; e++) p[e] = (short)f2b(acc[i][j][e]);
          *reinterpret_cast<s16x4*>(dst + (size_t)col * S_LEN + row0) = p;
        }
    } else {
      const float sc = (t == 0 || t == 3) ? SCALE : 1.0f;
#pragma unroll
      for (int i = 0; i < 4; i++)
#pragma unroll
        for (int j = 0; j < 4; j++)
#pragma unroll
          for (int e = 0; e < 4; e++) {
            int row = m0 + wm + i * 16 + lg * 4 + e;
            int col = wn + j * 16 + lr;
            dst[(size_t)row * DH + col] = f2b(acc[i][j][e] * sc);
          }
    }
  } else {
#pragma unroll
    for (int i = 0; i < 4; i++)
#pragma unroll
      for (int j = 0; j < 4; j++)
#pragma unroll
        for (int e = 0; e < 4; e++) {
          int row = m0 + wm + i * 16 + lg * 4 + e;
          int col = n0 + wn + j * 16 + lr;
          outf[(size_t)row * DMODEL + col] = acc[i][j][e];
        }
  }
}

// ---------------------------------------------------------------- diag correction
// per (qb, h): corr[row][col] = silu( (sigmoid(quku) masked col>row) @ vu )
// 1-D grid 128: h = bid&7 (XCD affinity), qb = bid>>3
__global__ void __launch_bounds__(256)
k_diag(const u16* __restrict__ qkvb, u16* __restrict__ corr) {
  __shared__ u16 PB[128][136];
  const int h = blockIdx.x & 7, qb = blockIdx.x >> 3;
  const int tid = threadIdx.x;
  const int w = tid >> 6, l = tid & 63;
  const int lr = l & 15, lg = l >> 4;
  const size_t hs = (size_t)S_LEN * DH;
  const u16* qu = qkvb + (size_t)(0 * HEADS + h) * hs;
  const u16* ku = qkvb + (size_t)(1 * HEADS + h) * hs;
  const u16* vuT = qkvb + (size_t)(2 * HEADS + h) * hs;  // [128][2048]
  const int rq = qb * 128 + w * 32;
  const u16* kub = ku + (size_t)qb * 128 * DH;
  f32x4 acc2[2][8] = {};
#pragma unroll
  for (int ks = 0; ks < 4; ks++) {
    s16x8 a0 = *reinterpret_cast<const s16x8*>(qu + (size_t)(rq + lr) * DH + ks * 32 + lg * 8);
    s16x8 a1 = *reinterpret_cast<const s16x8*>(qu + (size_t)(rq + 16 + lr) * DH + ks * 32 + lg * 8);
#pragma unroll
    for (int nf = 0; nf < 8; nf++) {
      s16x8 b = *reinterpret_cast<const s16x8*>(kub + (size_t)(nf * 16 + lr) * DH + ks * 32 + lg * 8);
      acc2[0][nf] = mfma16(a0, b, acc2[0][nf]);
      acc2[1][nf] = mfma16(a1, b, acc2[1][nf]);
    }
  }
#pragma unroll
  for (int mf = 0; mf < 2; mf++)
#pragma unroll
    for (int nf = 0; nf < 8; nf++)
#pragma unroll
      for (int e = 0; e < 4; e++) {
        int row = w * 32 + mf * 16 + lg * 4 + e;
        int col = nf * 16 + lr;
        float x = acc2[mf][nf][e];
        PB[row][col] = f2b((col > row) ? 1.f / (1.f + __expf(-x)) : 0.f);
        acc2[mf][nf][e] = 0.f;
      }
  // su = la @ vu  (PB rows are wave-private; vuT rows from global)
#pragma unroll
  for (int ks = 0; ks < 4; ks++) {
    s16x8 p0 = *reinterpret_cast<const s16x8*>(&PB[w * 32 + lr][ks * 32 + lg * 8]);
    s16x8 p1 = *reinterpret_cast<const s16x8*>(&PB[w * 32 + 16 + lr][ks * 32 + lg * 8]);
#pragma unroll
    for (int nf = 0; nf < 8; nf++) {
      s16x8 b = *reinterpret_cast<const s16x8*>(
          vuT + (size_t)(nf * 16 + lr) * S_LEN + qb * 128 + ks * 32 + lg * 8);
      acc2[0][nf] = mfma16(p0, b, acc2[0][nf]);
      acc2[1][nf] = mfma16(p1, b, acc2[1][nf]);
    }
  }
  u16* cp = corr + (size_t)(h * 16 + qb) * 16384;
#pragma unroll
  for (int mf = 0; mf < 2; mf++)
#pragma unroll
    for (int nf = 0; nf < 8; nf++)
#pragma unroll
      for (int e = 0; e < 4; e++) {
        int row = w * 32 + mf * 16 + lg * 4 + e;
        int col = nf * 16 + lr;
        float x = acc2[mf][nf][e];
        cp[row * 128 + col] = f2b(x / (1.f + __expf(-x)));
      }
}

// ---------------------------------------------------------------- attention phase 1
// 1-D grid 576: h = bid&7 (XCD pinning), slot = bid>>3. 512 thr / 8 waves x 16
// q-rows; <=2 key tiles. Double-buffered K (KA) and V^T (VB), 32KB each, staged
// via global_load_lds with 4-bit XOR swizzle (byte ^= (row&15)<<4 -> all 32
// banks on ds_read_b128). Pipeline: each stage issued one full compute phase
// before its vmcnt(0) drain (K(t+1) under PV(t), V(t+1) under QK(t+1)).
__global__ void __launch_bounds__(512, 4)
k_attn1(const u16* __restrict__ qkvb, const u16* __restrict__ corr,
        u16* __restrict__ opA, u16* __restrict__ opB, float* __restrict__ ml) {
  __shared__ u16 KA[128 * 128];   // K tile   [key j][d]   (swizzled content)
  __shared__ u16 VB[128 * 128];   // V^T tile [d][key j]   (swizzled content)
  __shared__ u16 PB[128][42];     // P quarter, wave-private rows
  const int h = blockIdx.x & 7, slot = blockIdx.x >> 3;
  const int qb = SQB2[slot];
  const int t0 = (slot - PFX2[qb]) * 2;
  const int nt = min(t0 + 2, qb + 1) - t0;  // 1 or 2 tiles
  const int tid = threadIdx.x;
  const int w = tid >> 6, l = tid & 63;
  const int lr = l & 15, lg = l >> 4;
  const size_t hs = (size_t)S_LEN * DH;
  const u16* qc = qkvb + (size_t)(3 * HEADS + h) * hs;
  const u16* kc = qkvb + (size_t)(4 * HEADS + h) * hs;
  const u16* vcT = qkvb + (size_t)(5 * HEADS + h) * hs;  // [128][2048]
  const int rq = qb * 128 + w * 16;

  f32x4 accO[8] = {};
  f32x4 accS[8];
  float mrun[4], lrun[4];
#pragma unroll
  for (int e = 0; e < 4; e++) { mrun[e] = -INFINITY; lrun[e] = 0.f; }

  // Q fragments in registers (once per slot)
  s16x8 aq[4];
#pragma unroll
  for (int ks = 0; ks < 4; ks++)
    aq[ks] = *reinterpret_cast<const s16x8*>(
        qc + (size_t)(rq + lr) * DH + ks * 32 + lg * 8);

  auto stageK = [&](int t) {
#pragma unroll
    for (int i = 0; i < 4; i++) {
      int r = w * 16 + i * 4 + (l >> 4);
      int s = l & 15;
      gll16(kc + (size_t)t * 128 * DH + r * DH + ((s ^ (r & 15)) * 8),
            KA + (w * 16 + i * 4) * 128);
    }
  };
  auto stageV = [&](int t) {
#pragma unroll
    for (int i = 0; i < 4; i++) {
      int r = w * 16 + i * 4 + (l >> 4);
      int s = l & 15;
      gll16(vcT + (size_t)r * S_LEN + t * 128 + ((s ^ (r & 15)) * 8),
            VB + (w * 16 + i * 4) * 128);
    }
  };
  auto qkTile = [&](bool dg) {
#pragma unroll
    for (int nf = 0; nf < 8; nf++) accS[nf] = f32x4{0.f, 0.f, 0.f, 0.f};
#pragma unroll
    for (int ks = 0; ks < 4; ks++)
#pragma unroll
      for (int nf = 0; nf < 8; nf++) {
        int o = ((nf * 16 + lr) * 256 + ks * 64 + lg * 16) ^ (lr << 4);
        s16x8 b = *reinterpret_cast<const s16x8*>((const char*)KA + o);
        accS[nf] = mfma16(aq[ks], b, accS[nf]);
      }
    if (dg) {
      const u16* cp = corr + (size_t)(h * 16 + qb) * 16384;
#pragma unroll
      for (int nf = 0; nf < 8; nf++)
#pragma unroll
        for (int e = 0; e < 4; e++) {
          int row = w * 16 + lg * 4 + e;
          int col = nf * 16 + lr;
          if (col > row) accS[nf][e] = -INFINITY;
          else accS[nf][e] -= b2f(cp[row * 128 + col]);
        }
    }
    // online softmax
#pragma unroll
    for (int e = 0; e < 4; e++) {
      float mx = accS[0][e];
#pragma unroll
      for (int nf = 1; nf < 8; nf++) mx = fmaxf(mx, accS[nf][e]);
#pragma unroll
      for (int off = 1; off < 16; off <<= 1) mx = fmaxf(mx, __shfl_xor(mx, off, 64));
      float mnew = fmaxf(mrun[e], mx);
      float f = __expf(mrun[e] - mnew);
      float rs = 0.f;
#pragma unroll
      for (int nf = 0; nf < 8; nf++) {
        float p = __expf(accS[nf][e] - mnew);
        accS[nf][e] = p;
        rs += p;
      }
#pragma unroll
      for (int off = 1; off < 16; off <<= 1) rs += __shfl_xor(rs, off, 64);
      lrun[e] = lrun[e] * f + rs;
      mrun[e] = mnew;
#pragma unroll
      for (int nf = 0; nf < 8; nf++) accO[nf][e] *= f;
    }
  };
  auto pvTile = [&]() {
#pragma unroll
    for (int qq = 0; qq < 4; qq++) {   // 32-key quarters; PB wave-private
#pragma unroll
      for (int jj = 0; jj < 2; jj++)
#pragma unroll
        for (int e = 0; e < 4; e++)
          PB[w * 16 + lg * 4 + e][jj * 16 + lr] = f2b(accS[qq * 2 + jj][e]);
      s16x8 p = *reinterpret_cast<const s16x8*>(&PB[w * 16 + lr][lg * 8]);
#pragma unroll
      for (int nf = 0; nf < 8; nf++) {
        int o = ((nf * 16 + lr) * 256 + qq * 64 + lg * 16) ^ (lr << 4);
        s16x8 bv = *reinterpret_cast<const s16x8*>((const char*)VB + o);
        accO[nf] = mfma16(p, bv, accO[nf]);
      }
    }
  };

  stageK(t0);
  stageV(t0);
  asm volatile("s_waitcnt vmcnt(4)" ::: "memory");  // K(t0) in; V in flight
  __syncthreads();
  if (nt == 2) {
    qkTile(false);                                   // V(t0) lands under this
    asm volatile("s_waitcnt vmcnt(0)" ::: "memory"); // V(t0) in
    __syncthreads();                                 // all waves done with KA
    stageK(t0 + 1);                                  // overwrite KA
    pvTile();                                        // K(t0+1) lands under this
    asm volatile("s_waitcnt vmcnt(0)" ::: "memory"); // K(t0+1) in
    __syncthreads();                                 // all waves done with VB
    stageV(t0 + 1);                                  // overwrite VB
    qkTile(t0 + 1 == qb);                            // V(t0+1) lands under this
    asm volatile("s_waitcnt vmcnt(0)" ::: "memory"); // V(t0+1) in
    __syncthreads();
    pvTile();
  } else {
    qkTile(t0 == qb);
    asm volatile("s_waitcnt vmcnt(0)" ::: "memory");
    __syncthreads();
    pvTile();
  }

  // ---- coalesced partial writeout: accO -> KA (LDS) -> global
  __syncthreads();
#pragma unroll
  for (int nf = 0; nf < 8; nf++)
#pragma unroll
    for (int e = 0; e < 4; e++)
      KA[(w * 16 + lg * 4 + e) * 128 + nf * 16 + lr] = f2b(accO[nf][e]);
  __syncthreads();
  const int gs = h * 72 + slot;
  u16* op = gs < 384 ? opA + (size_t)gs * 16384 : opB + (size_t)(gs - 384) * 16384;
#pragma unroll
  for (int i = 0; i < 4; i++)
    reinterpret_cast<s16x8*>(op)[tid + i * 512] =
        reinterpret_cast<const s16x8*>(KA)[tid + i * 512];
  if (lr == 0) {
    float* mlp = ml + (size_t)gs * 256;
#pragma unroll
    for (int e = 0; e < 4; e++) {
      int row = w * 16 + lg * 4 + e;
      mlp[row] = mrun[e];
      mlp[128 + row] = lrun[e];
    }
  }
}

// ---------------------------------------------------------------- phase 2 merge
// 1-D grid 128: h = bid&7 (same XCD as producer slots), qb = bid>>3
__global__ void __launch_bounds__(256)
k_attn2(const u16* __restrict__ opA, const u16* __restrict__ opB,
        const float* __restrict__ ml, u16* __restrict__ obuf) {
  const int h = blockIdx.x & 7, qb = blockIdx.x >> 3;
  const int nc = (qb >> 1) + 1;
  const int s0 = h * 72 + PFX2[qb];
  const int row = threadIdx.x >> 1, c0 = (threadIdx.x & 1) * 64;
  float mg = -INFINITY;
  for (int c = 0; c < nc; c++) mg = fmaxf(mg, ml[(size_t)(s0 + c) * 256 + row]);
  float acc[64];
#pragma unroll
  for (int k = 0; k < 64; k++) acc[k] = 0.f;
  float lsum = 0.f;
  for (int c = 0; c < nc; c++) {
    int gs = s0 + c;
    const float* mlp = ml + (size_t)gs * 256;
    float f = __expf(mlp[row] - mg);
    lsum += f * mlp[128 + row];
    const u16* p = (gs < 384 ? opA + (size_t)gs * 16384
                             : opB + (size_t)(gs - 384) * 16384) + row * 128 + c0;
#pragma unroll
    for (int k = 0; k < 8; k++) {
      s16x8 v = *reinterpret_cast<const s16x8*>(p + k * 8);
#pragma unroll
      for (int j = 0; j < 8; j++) acc[k * 8 + j] += f * b2f((u16)v[j]);
    }
  }
  float inv = 1.f / lsum;
  u16* dst = obuf + (size_t)(qb * 128 + row) * DMODEL + h * DH + c0;
#pragma unroll
  for (int k = 0; k < 8; k++) {
    s16x8 o;
#pragma unroll
    for (int j = 0; j < 8; j++) o[j] = (short)f2b(acc[k * 8 + j] * inv);
    *reinterpret_cast<s16x8*>(dst + k * 8) = o;
  }
}

// ---------------------------------------------------------------- launcher
extern "C" void kernel_launch(void* const* d_in, const int* in_sizes, int n_in,
                              void* d_out, int out_size, void* d_ws, size_t ws_size,
                              hipStream_t stream) {
  (void)in_sizes; (void)n_in; (void)out_size; (void)ws_size;
  const float* x = (const float*)d_in[0];
  const float* wqkv = (const float*)d_in[1];
  const float* wout = (const float*)d_in[2];
  char* ws = (char*)d_ws;
  u16* xb    = (u16*)(ws + 0);          // 4 MB; dead after gemm0
  u16* corrb = (u16*)(ws + 0);          // k_diag output (reuses xb)
  u16* wqT   = (u16*)(ws + 4194304);    // 12.58 MB; dead after gemm0
  u16* opB   = (u16*)(ws + 4194304);    // attn partials slots 384..575 (6.29 MB)
  float* mlb = (float*)(ws + 10485760); // 576*256*4 = 0.59 MB
  u16* woT   = (u16*)(ws + 16777216);   // 2 MB
  u16* qkvb  = (u16*)(ws + 18874368);   // 24 MB: [qu|ku|vuT|qc|kc|vcT] 4 MB each
  u16* opA   = (u16*)(ws + 18874368);   // attn partials slots 0..383 (12 MB,
                                        //   overwrites qu/ku/vuT after k_diag)
  u16* obuf  = (u16*)(ws + 44040192);   // 4 MB
  float* out = (float*)d_out;

  k_cast<<<2048, 256, 0, stream>>>(x, xb);
  k_transpose<<<dim3(192, 32), dim3(32, 8), 0, stream>>>(wqkv, wqT, DMODEL, NQKV);
  k_transpose<<<dim3(32, 32), dim3(32, 8), 0, stream>>>(wout, woT, DMODEL, DMODEL);
  k_gemm2<0><<<768, 256, 0, stream>>>(xb, wqT, qkvb, nullptr);
  k_diag<<<128, 256, 0, stream>>>(qkvb, corrb);
  k_attn1<<<576, 512, 0, stream>>>(qkvb, corrb, opA, opB, mlb);
  k_attn2<<<128, 256, 0, stream>>>(opA, opB, mlb, obuf);
  k_gemm2<1><<<dim3(8, 16), 256, 0, stream>>>(obuf, woT, nullptr, out);
}